// Round 1
// 315.997 us; speedup vs baseline: 1.1857x; 1.1857x over previous
//
#include <hip/hip_runtime.h>
#include <math.h>

#define BB 256
#define DD 4096
#define MAXR 31
#define NCAND 4
#define CAP 512
// filter: u < U_THRESH  =>  g(u) < 3.8 (incl. fp32 rounding slop). GUARD=4.0 check.
#define U_THRESH 0.9778f
#define GUARD 4.0f

typedef unsigned short u16;
typedef u16 u16x4 __attribute__((ext_vector_type(4)));
typedef u16 u16x8 __attribute__((ext_vector_type(8)));
typedef __bf16 bf16x8 __attribute__((ext_vector_type(8)));
typedef float f32x16 __attribute__((ext_vector_type(16)));

// ---------------- threefry2x32 (JAX schedule) ----------------
__device__ __forceinline__ void tf2x32(unsigned k0, unsigned k1, unsigned c0, unsigned c1,
                                       unsigned &o0, unsigned &o1) {
  unsigned ks2 = k0 ^ k1 ^ 0x1BD11BDAu;
  unsigned x0 = c0 + k0;
  unsigned x1 = c1 + k1;
#define TF_ROT(v, r) (((v) << (r)) | ((v) >> (32 - (r))))
#define TF_R(r) { x0 += x1; x1 = TF_ROT(x1, r); x1 ^= x0; }
  TF_R(13) TF_R(15) TF_R(26) TF_R(6)   x0 += k1;  x1 += ks2 + 1u;
  TF_R(17) TF_R(29) TF_R(16) TF_R(24)  x0 += ks2; x1 += k0 + 2u;
  TF_R(13) TF_R(15) TF_R(26) TF_R(6)   x0 += k0;  x1 += k1 + 3u;
  TF_R(17) TF_R(29) TF_R(16) TF_R(24)  x0 += k1;  x1 += ks2 + 4u;
  TF_R(13) TF_R(15) TF_R(26) TF_R(6)   x0 += ks2; x1 += k0 + 5u;
#undef TF_R
#undef TF_ROT
  o0 = x0; o1 = x1;
}

__device__ __forceinline__ unsigned tf_xor(unsigned k0, unsigned k1, unsigned c0, unsigned c1) {
  unsigned a, b; tf2x32(k0, k1, c0, c1, a, b); return a ^ b;
}

__device__ __forceinline__ float bits_to_unit(unsigned bits) {
  return __uint_as_float(0x3f800000u | (bits >> 9)) - 1.0f;
}

// ---------------- fast accurate double log (~1e-13 rel) ----------------
__device__ __forceinline__ double dlog(double x) {
  unsigned long long ub = (unsigned long long)__double_as_longlong(x);
  int e = (int)((ub >> 52) & 0x7FFull) - 1022;
  double m = __longlong_as_double((long long)((ub & 0x000FFFFFFFFFFFFFull) | 0x3FE0000000000000ull));
  if (m < 0.70710678118654752440) { m *= 2.0; e -= 1; }
  double r = (m - 1.0) / (m + 1.0);
  double z = r * r;
  double s = fma(z, fma(z, fma(z, fma(z, fma(z, fma(z, 1.0/15.0, 1.0/13.0),
                1.0/11.0), 1.0/9.0), 1.0/7.0), 1.0/5.0), 1.0/3.0);
  double t2 = 2.0 * r;
  return fma((double)e, 0.69314718055994530942, fma(t2 * z, s, t2));
}

// gumbel from uniform u (u>0), fp32-rounded at each log (matches XLA)
__device__ __forceinline__ float gumbel_from_u(float f) {
  float uu = (f == 0.0f) ? 1.17549435e-38f : f;
  float t1 = (float)dlog((double)uu);
  return -(float)dlog((double)(-t1));
}

__device__ __forceinline__ float gumbel_of(unsigned kk0, unsigned kk1, unsigned n) {
  return gumbel_from_u(bits_to_unit(tf_xor(kk0, kk1, 0u, n)));
}

__device__ __forceinline__ double blockReduce256(double v, double* lds) {
  #pragma unroll
  for (int off = 32; off > 0; off >>= 1) v += __shfl_down(v, off);
  __syncthreads();
  if ((threadIdx.x & 63) == 0) lds[threadIdx.x >> 6] = v;
  __syncthreads();
  return lds[0] + lds[1] + lds[2] + lds[3];
}

// ---------------- K0: all small RNG draws ----------------
__global__ void k_rng(unsigned* __restrict__ keys_out, int* __restrict__ radius,
                      float* __restrict__ u_acc) {
  int t = threadIdx.x;
  unsigned krad0, krad1, ksamp0, ksamp1, kacc0, kacc1;
  tf2x32(0u, 42u, 0u, 0u, krad0, krad1);
  tf2x32(0u, 42u, 0u, 1u, ksamp0, ksamp1);
  tf2x32(0u, 42u, 0u, 2u, kacc0, kacc1);
  if (t < MAXR) {
    unsigned a, c;
    tf2x32(ksamp0, ksamp1, 0u, (unsigned)t, a, c);
    keys_out[2*t] = a; keys_out[2*t+1] = c;
  }
  unsigned k10, k11, k20, k21;
  tf2x32(krad0, krad1, 0u, 0u, k10, k11);
  tf2x32(krad0, krad1, 0u, 1u, k20, k21);
  unsigned hi = tf_xor(k10, k11, 0u, (unsigned)t);
  unsigned lo = tf_xor(k20, k21, 0u, (unsigned)t);
  unsigned off = ((hi % 31u) * 4u + (lo % 31u)) % 31u;
  radius[t] = 1 + (int)off;
  unsigned ab = tf_xor(kacc0, kacc1, 0u, (unsigned)t);
  u_acc[t] = bits_to_unit(ab);
}

// ---------------- K1a: x -> bf16 (exact: x in {0,1}) ----------------
__global__ void k_xbf16(const float* __restrict__ x, u16* __restrict__ xb) {
  int i = blockIdx.x * 256 + threadIdx.x;
  float4 v = ((const float4*)x)[i];
  u16x4 o;
  o[0] = __builtin_bit_cast(u16, (__bf16)v.x);
  o[1] = __builtin_bit_cast(u16, (__bf16)v.y);
  o[2] = __builtin_bit_cast(u16, (__bf16)v.z);
  o[3] = __builtin_bit_cast(u16, (__bf16)v.w);
  *(u16x4*)&xb[4*i] = o;
}

// ---------------- K1b: bf16 3-split MFMA GEMM (fused W split) ----------------
// grad_part = x @ (Wh + Wl + Wl2), fp32 MFMA accumulation.
// x exact in bf16 (binary); W symmetric => W[n][k] == W[k][n], so B^T reads are
// plain row-major reads of W. Error vs fp32 GEMM: ordering-class ~1e-6 + 5e-9 residual.
__device__ __forceinline__ void split3(float w, u16 &h, u16 &l, u16 &q) {
  __bf16 hb = (__bf16)w;
  float r = w - (float)hb;        // exact (Sterbenz-style: low bits of w)
  __bf16 lb = (__bf16)r;
  float r2 = r - (float)lb;       // exact
  __bf16 qb = (__bf16)r2;
  h = __builtin_bit_cast(u16, hb);
  l = __builtin_bit_cast(u16, lb);
  q = __builtin_bit_cast(u16, qb);
}

__global__ __launch_bounds__(256, 2) void k_gemm_mfma(
    const u16* __restrict__ xb, const float* __restrict__ W,
    float* __restrict__ Cpart, int klen) {
  int nt = blockIdx.x, mt = blockIdx.y, kc = blockIdx.z;
  int t = threadIdx.x;
  int k0 = kc * klen;

  // k-group-major LDS: [kg][row][8 bf16] -> 16B chunks, lane-contiguous ds_read_b128
  __shared__ alignas(16) u16 As[4][128][8];       // 8 KB  (x tile, bf16)
  __shared__ alignas(16) u16 Bs[3][4][128][8];    // 24 KB (Wh/Wl/Wl2 tiles)

  const u16*   xrow = xb + (size_t)(mt * 128) * DD + k0;
  const float* wrow = W  + (size_t)(nt * 128) * DD + k0;   // W symmetric: rows n give B^T

  int am  = t >> 2, akg = t & 3;        // A chunks: (m=am,kg) and (m=am+64,kg)
  int bn  = t >> 1, bko = (t & 1) * 16; // B: row n=bn, 16 fp32 at k-offset bko
  int bkg = (t & 1) * 2;

  uint4  aR0, aR1;
  float4 bR0, bR1, bR2, bR3;

  int nsteps = klen / 32;

  { // prefetch step 0
    const u16* ap = xrow + (size_t)am * DD + akg * 8;
    aR0 = *(const uint4*)ap;
    aR1 = *(const uint4*)(ap + (size_t)64 * DD);
    const float* wp = wrow + (size_t)bn * DD + bko;
    bR0 = *(const float4*)(wp);
    bR1 = *(const float4*)(wp + 4);
    bR2 = *(const float4*)(wp + 8);
    bR3 = *(const float4*)(wp + 12);
  }

  int wid = t >> 6, lane = t & 63;
  int wr = (wid >> 1) * 64, wc = (wid & 1) * 64;  // wave's 64x64 quadrant
  int lm = lane & 31, lh = lane >> 5;

  f32x16 acc[2][2];
  #pragma unroll
  for (int i = 0; i < 2; i++)
    #pragma unroll
    for (int j = 0; j < 2; j++)
      #pragma unroll
      for (int r = 0; r < 16; r++) acc[i][j][r] = 0.0f;

  for (int s = 0; s < nsteps; s++) {
    __syncthreads();
    // ---- write A tile
    *(uint4*)&As[akg][am][0]      = aR0;
    *(uint4*)&As[akg][am + 64][0] = aR1;
    // ---- convert + write B tiles (3 planes)
    {
      float wv[16];
      *(float4*)&wv[0] = bR0; *(float4*)&wv[4]  = bR1;
      *(float4*)&wv[8] = bR2; *(float4*)&wv[12] = bR3;
      u16x8 ph[2], pl[2], pq[2];
      #pragma unroll
      for (int g = 0; g < 2; g++)
        #pragma unroll
        for (int i = 0; i < 8; i++) {
          u16 h, l, q;
          split3(wv[g * 8 + i], h, l, q);
          ph[g][i] = h; pl[g][i] = l; pq[g][i] = q;
        }
      #pragma unroll
      for (int g = 0; g < 2; g++) {
        *(u16x8*)&Bs[0][bkg + g][bn][0] = ph[g];
        *(u16x8*)&Bs[1][bkg + g][bn][0] = pl[g];
        *(u16x8*)&Bs[2][bkg + g][bn][0] = pq[g];
      }
    }
    __syncthreads();
    // ---- prefetch next step (hidden under MFMA)
    if (s + 1 < nsteps) {
      int kk = (s + 1) * 32;
      const u16* ap = xrow + (size_t)am * DD + kk + akg * 8;
      aR0 = *(const uint4*)ap;
      aR1 = *(const uint4*)(ap + (size_t)64 * DD);
      const float* wp = wrow + (size_t)bn * DD + kk + bko;
      bR0 = *(const float4*)(wp);
      bR1 = *(const float4*)(wp + 4);
      bR2 = *(const float4*)(wp + 8);
      bR3 = *(const float4*)(wp + 12);
    }
    // ---- compute: 24 x v_mfma_f32_32x32x16_bf16
    bf16x8 af[2][2];
    #pragma unroll
    for (int mf = 0; mf < 2; mf++)
      #pragma unroll
      for (int h = 0; h < 2; h++)
        af[mf][h] = *(const bf16x8*)&As[2 * h + lh][wr + mf * 32 + lm][0];
    #pragma unroll
    for (int p = 0; p < 3; p++) {
      bf16x8 bfr[2][2];
      #pragma unroll
      for (int nf = 0; nf < 2; nf++)
        #pragma unroll
        for (int h = 0; h < 2; h++)
          bfr[nf][h] = *(const bf16x8*)&Bs[p][2 * h + lh][wc + nf * 32 + lm][0];
      #pragma unroll
      for (int mf = 0; mf < 2; mf++)
        #pragma unroll
        for (int nf = 0; nf < 2; nf++) {
          acc[mf][nf] = __builtin_amdgcn_mfma_f32_32x32x16_bf16(af[mf][0], bfr[nf][0], acc[mf][nf], 0, 0, 0);
          acc[mf][nf] = __builtin_amdgcn_mfma_f32_32x32x16_bf16(af[mf][1], bfr[nf][1], acc[mf][nf], 0, 0, 0);
        }
    }
  }

  // ---- epilogue: C/D layout (32x32): col=lane&31, row=(reg&3)+8*(reg>>2)+4*(lane>>5)
  float* Cp = Cpart + (size_t)kc * ((size_t)BB * DD);
  #pragma unroll
  for (int mf = 0; mf < 2; mf++)
    #pragma unroll
    for (int nf = 0; nf < 2; nf++) {
      int col   = nt * 128 + wc + nf * 32 + lm;
      int rbase = mt * 128 + wr + mf * 32 + 4 * lh;
      #pragma unroll
      for (int r = 0; r < 16; r++) {
        int row = rbase + (r & 3) + 8 * (r >> 2);
        Cp[(size_t)row * DD + col] = acc[mf][nf][r];
      }
    }
}

// ---------------- K1c: reduce split-K, add bias, make sc_x ----------------
__global__ void k_reduce(const float* __restrict__ Cpart, const float* __restrict__ bias,
                         const float* __restrict__ x, float* __restrict__ grad,
                         float* __restrict__ sc, int KS) {
  int i = blockIdx.x * 256 + threadIdx.x;
  float acc = 0.0f;
  for (int kc = 0; kc < KS; kc++) acc += Cpart[(size_t)kc * BB * DD + i];
  float g = acc + bias[i & (DD-1)];
  grad[i] = g;
  float xv = x[i];
  sc[i] = (1.0f - 2.0f*xv) * g * 0.5f;
}

// ---------------- K2: score_x + per-row max of sc_x ----------------
__global__ __launch_bounds__(256) void k_score(const float* __restrict__ x, const float* __restrict__ grad,
                                               const float* __restrict__ bias, double* __restrict__ score,
                                               float* __restrict__ scmax) {
  int b = blockIdx.x, t = threadIdx.x;
  double s1 = 0.0, s2 = 0.0;
  float mx = -INFINITY;
  for (int k = 0; k < 16; k++) {
    int d = t + 256*k; size_t o = (size_t)b*DD + d;
    float xvf = x[o];
    float gv = grad[o];
    float scv = (1.0f - 2.0f*xvf) * gv * 0.5f;  // identical rounding to k_reduce
    mx = fmaxf(mx, scv);
    double xv = xvf;
    s1 += xv * (double)gv;
    s2 += xv * (double)bias[d];
  }
  __shared__ double lds[4];
  double S1 = blockReduce256(s1, lds);
  double S2 = blockReduce256(s2, lds);
  // max reduce
  #pragma unroll
  for (int off = 32; off > 0; off >>= 1) mx = fmaxf(mx, __shfl_down(mx, off));
  __shared__ float lmx[4];
  __syncthreads();
  if ((t & 63) == 0) lmx[t >> 6] = mx;
  __syncthreads();
  if (t == 0) {
    score[b] = 0.5 * (S1 + S2);
    scmax[b] = fmaxf(fmaxf(lmx[0], lmx[1]), fmaxf(lmx[2], lmx[3]));
  }
}

// ---------------- K4: per (row,step) top-4 via u-filter + exact fallback ----------------
__global__ __launch_bounds__(256) void k_cand(const float* __restrict__ sc_x,
                                              const unsigned* __restrict__ keys,
                                              const float* __restrict__ scmax,
                                              int* __restrict__ cand_i) {
  int blk = blockIdx.x;
  int b = blk / MAXR, j = blk % MAXR;
  unsigned kk0 = keys[2*j], kk1 = keys[2*j+1];
  int t = threadIdx.x;
  unsigned base = (unsigned)(b * DD);

  __shared__ int cnt;
  __shared__ int   lidx[CAP];
  __shared__ float lu[CAP];
  __shared__ float win_v_s;
  __shared__ int   win_i_s;
  __shared__ float ls_v[4];
  __shared__ int   ls_i[4];
  if (t == 0) cnt = 0;
  __syncthreads();

  // phase 1: threefry + uniform + cheap filter (the 97.8% fast path)
  #pragma unroll
  for (int p = 0; p < 16; p++) {
    int d = t + 256*p;
    unsigned bits = tf_xor(kk0, kk1, 0u, base + (unsigned)d);
    float f = bits_to_unit(bits);
    if (f >= U_THRESH) {
      int pos = atomicAdd(&cnt, 1);
      if (pos < CAP) { lidx[pos] = d; lu[pos] = f; }
    }
  }
  __syncthreads();
  int n = cnt;
  bool need_fallback = (n > CAP) || (n < NCAND);

  if (!need_fallback) {
    // phase 2: exact gumbel + top-4 over <=512 candidates (2 per thread)
    float v[2]; int di[2]; unsigned alive = 0u;
    #pragma unroll
    for (int q = 0; q < 2; q++) {
      int idx = t + 256*q;
      if (idx < n) {
        int d = lidx[idx];
        v[q] = sc_x[(size_t)b*DD + d] + gumbel_from_u(lu[idx]);
        di[q] = d;
        alive |= (1u << q);
      } else { v[q] = -INFINITY; di[q] = 0x7FFFFFFF; }
    }
    float v4 = -INFINITY;
    for (int r = 0; r < NCAND; r++) {
      float bv = -INFINITY; int bi = 0x7FFFFFFF;
      #pragma unroll
      for (int q = 0; q < 2; q++)
        if (((alive >> q) & 1u) && (v[q] > bv || (v[q] == bv && di[q] < bi))) { bv = v[q]; bi = di[q]; }
      #pragma unroll
      for (int off = 32; off > 0; off >>= 1) {
        float ov = __shfl_down(bv, off);
        int   oi = __shfl_down(bi, off);
        if (ov > bv || (ov == bv && oi < bi)) { bv = ov; bi = oi; }
      }
      if ((t & 63) == 0) { ls_v[t >> 6] = bv; ls_i[t >> 6] = bi; }
      __syncthreads();
      if (t == 0) {
        float fv = ls_v[0]; int fi = ls_i[0];
        #pragma unroll
        for (int w = 1; w < 4; w++)
          if (ls_v[w] > fv || (ls_v[w] == fv && ls_i[w] < fi)) { fv = ls_v[w]; fi = ls_i[w]; }
        win_v_s = fv; win_i_s = fi;
        cand_i[(size_t)blk * NCAND + r] = fi;
      }
      __syncthreads();
      int wd = win_i_s;
      v4 = win_v_s;
      #pragma unroll
      for (int q = 0; q < 2; q++) if (di[q] == wd) alive &= ~(1u << q);
    }
    // guarantee: every skipped element has v < scmax + 3.8 < scmax + GUARD
    if (v4 >= scmax[b] + GUARD) return;
    need_fallback = true;
    __syncthreads();
  }

  // fallback: full exact computation (statistically ~never; preserves exactness)
  {
    float v[16];
    #pragma unroll
    for (int p = 0; p < 16; p++) {
      int d = t + 256*p;
      v[p] = sc_x[(size_t)b*DD + d] + gumbel_of(kk0, kk1, base + (unsigned)d);
    }
    unsigned alive = 0xFFFFu;
    float lv = -INFINITY; int li = 0x7FFFFFFF;
    #pragma unroll
    for (int p = 0; p < 16; p++)
      if (v[p] > lv) { lv = v[p]; li = t + 256*p; }
    for (int r = 0; r < NCAND; r++) {
      float bv = lv; int bi = li;
      #pragma unroll
      for (int off = 32; off > 0; off >>= 1) {
        float ov = __shfl_down(bv, off);
        int   oi = __shfl_down(bi, off);
        if (ov > bv || (ov == bv && oi < bi)) { bv = ov; bi = oi; }
      }
      if ((t & 63) == 0) { ls_v[t >> 6] = bv; ls_i[t >> 6] = bi; }
      __syncthreads();
      if (t == 0) {
        float fv = ls_v[0]; int fi = ls_i[0];
        #pragma unroll
        for (int w = 1; w < 4; w++)
          if (ls_v[w] > fv || (ls_v[w] == fv && ls_i[w] < fi)) { fv = ls_v[w]; fi = ls_i[w]; }
        win_i_s = fi;
        cand_i[(size_t)blk * NCAND + r] = fi;
      }
      __syncthreads();
      if (r < NCAND - 1) {
        int wi = win_i_s;
        if (t == (wi & 255)) {
          alive &= ~(1u << (wi >> 8));
          lv = -INFINITY; li = 0x7FFFFFFF;
          #pragma unroll
          for (int p = 0; p < 16; p++)
            if (((alive >> p) & 1u) && v[p] > lv) { lv = v[p]; li = t + 256*p; }
        }
      }
    }
  }
}

// ---------------- K5: per-row blocked-chain resolution w/ exact fallback ----------------
__global__ __launch_bounds__(256) void k_select(const int* __restrict__ cand_i,
                                                const float* __restrict__ sc_x,
                                                const unsigned* __restrict__ keys,
                                                int* __restrict__ idx_all) {
  int b = blockIdx.x, t = threadIdx.x;
  __shared__ unsigned mask[128];
  __shared__ int pick_s;
  __shared__ float ls_v[4];
  __shared__ int   ls_i[4];
  if (t < 128) mask[t] = 0u;
  __syncthreads();
  for (int j = 0; j < MAXR; j++) {
    if (t == 0) {
      const int* ci = &cand_i[(size_t)(b*MAXR + j) * NCAND];
      int pick = -1;
      #pragma unroll
      for (int r = 0; r < NCAND; r++) {
        int idx = ci[r];
        if (pick < 0 && !((mask[idx >> 5] >> (idx & 31)) & 1u)) pick = idx;
      }
      pick_s = pick;
    }
    __syncthreads();
    if (pick_s < 0) {
      unsigned kk0 = keys[2*j], kk1 = keys[2*j+1];
      float lv = -INFINITY; int li = 0x7FFFFFFF;
      for (int p = 0; p < 16; p++) {
        int d = t + 256*p;
        if ((mask[d >> 5] >> (d & 31)) & 1u) continue;
        float vv = sc_x[(size_t)b*DD + d] + gumbel_of(kk0, kk1, (unsigned)(b*DD + d));
        if (vv > lv || (vv == lv && d < li)) { lv = vv; li = d; }
      }
      float bv = lv; int bi = li;
      #pragma unroll
      for (int off = 32; off > 0; off >>= 1) {
        float ov = __shfl_down(bv, off);
        int   oi = __shfl_down(bi, off);
        if (ov > bv || (ov == bv && oi < bi)) { bv = ov; bi = oi; }
      }
      if ((t & 63) == 0) { ls_v[t >> 6] = bv; ls_i[t >> 6] = bi; }
      __syncthreads();
      if (t == 0) {
        float fv = ls_v[0]; int fi = ls_i[0];
        #pragma unroll
        for (int w = 1; w < 4; w++)
          if (ls_v[w] > fv || (ls_v[w] == fv && ls_i[w] < fi)) { fv = ls_v[w]; fi = ls_i[w]; }
        pick_s = fi;
      }
      __syncthreads();
    }
    if (t == 0) {
      int pk = pick_s;
      idx_all[b*MAXR + j] = pk;
      mask[pk >> 5] |= (1u << (pk & 31));
    }
    __syncthreads();
  }
}

// ---------------- K6: y, grad_y (incremental), sc_y, score_y ----------------
__global__ __launch_bounds__(256) void k_y(const float* __restrict__ x, const float* __restrict__ W,
    const float* __restrict__ bias, const float* __restrict__ grad_x,
    const int* __restrict__ idx_all, const int* __restrict__ radius,
    float* __restrict__ yv, float* __restrict__ sc_y, double* __restrict__ score_y) {
  int b = blockIdx.x, t = threadIdx.x;
  __shared__ int   fidx[MAXR];
  __shared__ float fsgn[MAXR];
  int nf = radius[b];
  if (t < nf) {
    int id = idx_all[b*MAXR + t];
    fidx[t] = id;
    fsgn[t] = 1.0f - 2.0f * x[(size_t)b*DD + id];
  }
  __syncthreads();
  double s1 = 0.0, s2 = 0.0;
  for (int k = 0; k < 16; k++) {
    int d = t + 256*k;
    size_t o = (size_t)b*DD + d;
    float g = grad_x[o];
    float xval = x[o];
    float yval = xval;
    for (int jj = 0; jj < nf; jj++) {
      g = fmaf(fsgn[jj], W[(size_t)fidx[jj]*DD + d], g);
      if (fidx[jj] == d) yval = 1.0f - xval;
    }
    yv[o] = yval;
    sc_y[o] = (1.0f - 2.0f*yval) * g * 0.5f;
    s1 += (double)yval * (double)g;
    s2 += (double)yval * (double)bias[d];
  }
  __shared__ double lds[4];
  double S1 = blockReduce256(s1, lds);
  double S2 = blockReduce256(s2, lds);
  if (t == 0) score_y[b] = 0.5 * (S1 + S2);
}

// ---------------- K7: masked log-softmax sums, accept, output ----------------
__global__ __launch_bounds__(256) void k_accept(const float* __restrict__ x, const float* __restrict__ yv,
    const float* __restrict__ sc_x, const float* __restrict__ sc_y,
    const int* __restrict__ idx_all, const int* __restrict__ radius,
    const double* __restrict__ score_x, const double* __restrict__ score_y,
    const float* __restrict__ u_acc, float* __restrict__ out) {
  int b = blockIdx.x, t = threadIdx.x;
  double sx = 0.0, sy = 0.0;
  for (int k = 0; k < 16; k++) {
    int d = t + 256*k; size_t o = (size_t)b*DD + d;
    sx += exp((double)sc_x[o]);
    sy += exp((double)sc_y[o]);
  }
  __shared__ double lds[4];
  double S = blockReduce256(sx, lds);
  double T = blockReduce256(sy, lds);
  __shared__ float accf;
  if (t == 0) {
    int nf = radius[b];
    const int* ia = &idx_all[b*MAXR];
    double lf = 0.0, pre = 0.0;
    for (int jj = 0; jj < MAXR; jj++) {
      int id = ia[jj];
      double scv = (double)sc_x[(size_t)b*DD + id];
      if (jj < nf) lf += scv - dlog(S - pre);
      pre += exp(scv);
    }
    double lb = 0.0, suf = 0.0;
    for (int jj = MAXR-1; jj >= 0; jj--) {
      int id = ia[jj];
      double scv = (double)sc_y[(size_t)b*DD + id];
      if (jj < nf) lb += scv - dlog(T - suf);
      suf += exp(scv);
    }
    double log_acc = (lb + score_y[b]) - (lf + score_x[b]);
    accf = (exp(log_acc) >= (double)u_acc[b]) ? 1.0f : 0.0f;
  }
  __syncthreads();
  float a = accf;
  for (int k = 0; k < 16; k++) {
    int d = t + 256*k; size_t o = (size_t)b*DD + d;
    out[o] = a * yv[o] + (1.0f - a) * x[o];
  }
}

extern "C" void kernel_launch(void* const* d_in, const int* in_sizes, int n_in,
                              void* d_out, int out_size, void* d_ws, size_t ws_size,
                              hipStream_t stream) {
  const float* x    = (const float*)d_in[0];
  const float* W    = (const float*)d_in[1];
  const float* bias = (const float*)d_in[2];
  float* out = (float*)d_out;
  char* ws = (char*)d_ws;
  const size_t MB = 1ull << 20;

  float*    grad_x  = (float*)   (ws + 0*MB);
  float*    sc_x    = (float*)   (ws + 4*MB);
  float*    sc_y    = (float*)   (ws + 8*MB);
  float*    yv      = (float*)   (ws + 12*MB);
  u16*      xb      = (u16*)     (ws + 16*MB);   // x as bf16 (2 MB)
  int*      cand_i  = (int*)     (ws + 20*MB);
  int*      idx_all = (int*)     (ws + 21*MB);
  int*      radius  = (int*)     (ws + 21*MB + 64*1024);
  float*    u_acc   = (float*)   (ws + 21*MB + 68*1024);
  unsigned* keys    = (unsigned*)(ws + 21*MB + 72*1024);
  double*   score_x = (double*)  (ws + 21*MB + 80*1024);
  double*   score_y = (double*)  (ws + 21*MB + 96*1024);
  float*    scmax   = (float*)   (ws + 21*MB + 112*1024);
  float*    Cpart   = (float*)   (ws + 22*MB);

  size_t base = 22*MB;
  int KS = 1;
  if      (ws_size >= base + 32*MB) KS = 8;
  else if (ws_size >= base + 16*MB) KS = 4;
  else if (ws_size >= base +  8*MB) KS = 2;

  k_rng      <<<1, 256, 0, stream>>>(keys, radius, u_acc);
  k_xbf16    <<<BB*DD/1024, 256, 0, stream>>>(x, xb);
  k_gemm_mfma<<<dim3(DD/128, BB/128, KS), 256, 0, stream>>>(xb, W, Cpart, DD/KS);
  k_reduce   <<<BB*DD/256, 256, 0, stream>>>(Cpart, bias, x, grad_x, sc_x, KS);
  k_score    <<<BB, 256, 0, stream>>>(x, grad_x, bias, score_x, scmax);
  k_cand     <<<BB*MAXR, 256, 0, stream>>>(sc_x, keys, scmax, cand_i);
  k_select   <<<BB, 256, 0, stream>>>(cand_i, sc_x, keys, idx_all);
  k_y        <<<BB, 256, 0, stream>>>(x, W, bias, grad_x, idx_all, radius, yv, sc_y, score_y);
  k_accept   <<<BB, 256, 0, stream>>>(x, yv, sc_x, sc_y, idx_all, radius, score_x, score_y, u_acc, out);
}

// Round 2
// 309.590 us; speedup vs baseline: 1.2102x; 1.0207x over previous
//
#include <hip/hip_runtime.h>
#include <math.h>

#define BB 256
#define DD 4096
#define MAXR 31
#define NCAND 4
#define CAPG 192
// filter: u < U_THRESH  =>  g(u) < 3.8 (incl. fp32 rounding slop). GUARD=4.0 check.
#define U_THRESH 0.9778f
#define GUARD 4.0f

typedef unsigned short u16;
typedef u16 u16x4 __attribute__((ext_vector_type(4)));
typedef u16 u16x8 __attribute__((ext_vector_type(8)));
typedef __bf16 bf16x8 __attribute__((ext_vector_type(8)));
typedef float f32x16 __attribute__((ext_vector_type(16)));

// ---------------- threefry2x32 (JAX schedule) ----------------
__device__ __forceinline__ void tf2x32(unsigned k0, unsigned k1, unsigned c0, unsigned c1,
                                       unsigned &o0, unsigned &o1) {
  unsigned ks2 = k0 ^ k1 ^ 0x1BD11BDAu;
  unsigned x0 = c0 + k0;
  unsigned x1 = c1 + k1;
#define TF_ROT(v, r) (((v) << (r)) | ((v) >> (32 - (r))))
#define TF_R(r) { x0 += x1; x1 = TF_ROT(x1, r); x1 ^= x0; }
  TF_R(13) TF_R(15) TF_R(26) TF_R(6)   x0 += k1;  x1 += ks2 + 1u;
  TF_R(17) TF_R(29) TF_R(16) TF_R(24)  x0 += ks2; x1 += k0 + 2u;
  TF_R(13) TF_R(15) TF_R(26) TF_R(6)   x0 += k0;  x1 += k1 + 3u;
  TF_R(17) TF_R(29) TF_R(16) TF_R(24)  x0 += k1;  x1 += ks2 + 4u;
  TF_R(13) TF_R(15) TF_R(26) TF_R(6)   x0 += ks2; x1 += k0 + 5u;
#undef TF_R
#undef TF_ROT
  o0 = x0; o1 = x1;
}

__device__ __forceinline__ unsigned tf_xor(unsigned k0, unsigned k1, unsigned c0, unsigned c1) {
  unsigned a, b; tf2x32(k0, k1, c0, c1, a, b); return a ^ b;
}

__device__ __forceinline__ float bits_to_unit(unsigned bits) {
  return __uint_as_float(0x3f800000u | (bits >> 9)) - 1.0f;
}

// ---------------- fast accurate double log (~1e-13 rel) ----------------
__device__ __forceinline__ double dlog(double x) {
  unsigned long long ub = (unsigned long long)__double_as_longlong(x);
  int e = (int)((ub >> 52) & 0x7FFull) - 1022;
  double m = __longlong_as_double((long long)((ub & 0x000FFFFFFFFFFFFFull) | 0x3FE0000000000000ull));
  if (m < 0.70710678118654752440) { m *= 2.0; e -= 1; }
  double r = (m - 1.0) / (m + 1.0);
  double z = r * r;
  double s = fma(z, fma(z, fma(z, fma(z, fma(z, fma(z, 1.0/15.0, 1.0/13.0),
                1.0/11.0), 1.0/9.0), 1.0/7.0), 1.0/5.0), 1.0/3.0);
  double t2 = 2.0 * r;
  return fma((double)e, 0.69314718055994530942, fma(t2 * z, s, t2));
}

// gumbel from uniform u (u>0), fp32-rounded at each log (matches XLA)
__device__ __forceinline__ float gumbel_from_u(float f) {
  float uu = (f == 0.0f) ? 1.17549435e-38f : f;
  float t1 = (float)dlog((double)uu);
  return -(float)dlog((double)(-t1));
}

__device__ __forceinline__ float gumbel_of(unsigned kk0, unsigned kk1, unsigned n) {
  return gumbel_from_u(bits_to_unit(tf_xor(kk0, kk1, 0u, n)));
}

__device__ __forceinline__ double blockReduce256(double v, double* lds) {
  #pragma unroll
  for (int off = 32; off > 0; off >>= 1) v += __shfl_down(v, off);
  __syncthreads();
  if ((threadIdx.x & 63) == 0) lds[threadIdx.x >> 6] = v;
  __syncthreads();
  return lds[0] + lds[1] + lds[2] + lds[3];
}

// ---------------- K0: all small RNG draws ----------------
__global__ void k_rng(unsigned* __restrict__ keys_out, int* __restrict__ radius,
                      float* __restrict__ u_acc) {
  int t = threadIdx.x;
  unsigned krad0, krad1, ksamp0, ksamp1, kacc0, kacc1;
  tf2x32(0u, 42u, 0u, 0u, krad0, krad1);
  tf2x32(0u, 42u, 0u, 1u, ksamp0, ksamp1);
  tf2x32(0u, 42u, 0u, 2u, kacc0, kacc1);
  if (t < MAXR) {
    unsigned a, c;
    tf2x32(ksamp0, ksamp1, 0u, (unsigned)t, a, c);
    keys_out[2*t] = a; keys_out[2*t+1] = c;
  }
  unsigned k10, k11, k20, k21;
  tf2x32(krad0, krad1, 0u, 0u, k10, k11);
  tf2x32(krad0, krad1, 0u, 1u, k20, k21);
  unsigned hi = tf_xor(k10, k11, 0u, (unsigned)t);
  unsigned lo = tf_xor(k20, k21, 0u, (unsigned)t);
  unsigned off = ((hi % 31u) * 4u + (lo % 31u)) % 31u;
  radius[t] = 1 + (int)off;
  unsigned ab = tf_xor(kacc0, kacc1, 0u, (unsigned)t);
  u_acc[t] = bits_to_unit(ab);
}

// ---------------- K1a: x -> bf16 (exact: x in {0,1}) ----------------
__global__ void k_xbf16(const float* __restrict__ x, u16* __restrict__ xb) {
  int i = blockIdx.x * 256 + threadIdx.x;
  float4 v = ((const float4*)x)[i];
  u16x4 o;
  o[0] = __builtin_bit_cast(u16, (__bf16)v.x);
  o[1] = __builtin_bit_cast(u16, (__bf16)v.y);
  o[2] = __builtin_bit_cast(u16, (__bf16)v.z);
  o[3] = __builtin_bit_cast(u16, (__bf16)v.w);
  *(u16x4*)&xb[4*i] = o;
}

// ---------------- W 3-way bf16 split ----------------
__device__ __forceinline__ void split3(float w, u16 &h, u16 &l, u16 &q) {
  __bf16 hb = (__bf16)w;
  float r = w - (float)hb;        // exact
  __bf16 lb = (__bf16)r;
  float r2 = r - (float)lb;       // exact
  __bf16 qb = (__bf16)r2;
  h = __builtin_bit_cast(u16, hb);
  l = __builtin_bit_cast(u16, lb);
  q = __builtin_bit_cast(u16, qb);
}

// ---------------- K_MEGA: heterogeneous blocks ----------------
// blocks [0, ngemm):      bf16 3-split MFMA GEMM (matrix pipe)
// blocks [ngemm, +B*MAXR): threefry u-filter for k_cand phase 1 (VALU pipe)
// Co-resident on each CU: MFMA waves + VALU waves overlap (time ~ max, not sum).
__global__ __launch_bounds__(256, 2) void k_mega(
    const u16* __restrict__ xb, const float* __restrict__ W,
    float* __restrict__ Cpart, int klen, int ngemm,
    const unsigned* __restrict__ keys,
    u16* __restrict__ flt_list, int* __restrict__ flt_cnt) {
  int t = threadIdx.x;

  if ((int)blockIdx.x < ngemm) {
    // ================= GEMM role =================
    int g = blockIdx.x;
    int nt = g & 31, mt = (g >> 5) & 1, kc = g >> 6;
    int k0 = kc * klen;

    __shared__ alignas(16) u16 As[4][128][8];       // 8 KB
    __shared__ alignas(16) u16 Bs[3][4][128][8];    // 24 KB

    const u16*   xrow = xb + (size_t)(mt * 128) * DD + k0;
    const float* wrow = W  + (size_t)(nt * 128) * DD + k0;   // W symmetric

    int am  = t >> 2, akg = t & 3;
    int bn  = t >> 1, bko = (t & 1) * 16;
    int bkg = (t & 1) * 2;

    uint4  aR0, aR1;
    float4 bR0, bR1, bR2, bR3;
    int nsteps = klen / 32;

    { // prefetch step 0
      const u16* ap = xrow + (size_t)am * DD + akg * 8;
      aR0 = *(const uint4*)ap;
      aR1 = *(const uint4*)(ap + (size_t)64 * DD);
      const float* wp = wrow + (size_t)bn * DD + bko;
      bR0 = *(const float4*)(wp);
      bR1 = *(const float4*)(wp + 4);
      bR2 = *(const float4*)(wp + 8);
      bR3 = *(const float4*)(wp + 12);
    }

    int wid = t >> 6, lane = t & 63;
    int wr = (wid >> 1) * 64, wc = (wid & 1) * 64;
    int lm = lane & 31, lh = lane >> 5;

    f32x16 acc[2][2];
    #pragma unroll
    for (int i = 0; i < 2; i++)
      #pragma unroll
      for (int j = 0; j < 2; j++)
        #pragma unroll
        for (int r = 0; r < 16; r++) acc[i][j][r] = 0.0f;

    for (int s = 0; s < nsteps; s++) {
      __syncthreads();
      *(uint4*)&As[akg][am][0]      = aR0;
      *(uint4*)&As[akg][am + 64][0] = aR1;
      {
        float wv[16];
        *(float4*)&wv[0] = bR0; *(float4*)&wv[4]  = bR1;
        *(float4*)&wv[8] = bR2; *(float4*)&wv[12] = bR3;
        u16x8 ph[2], pl[2], pq[2];
        #pragma unroll
        for (int g2 = 0; g2 < 2; g2++)
          #pragma unroll
          for (int i = 0; i < 8; i++) {
            u16 h, l, q;
            split3(wv[g2 * 8 + i], h, l, q);
            ph[g2][i] = h; pl[g2][i] = l; pq[g2][i] = q;
          }
        #pragma unroll
        for (int g2 = 0; g2 < 2; g2++) {
          *(u16x8*)&Bs[0][bkg + g2][bn][0] = ph[g2];
          *(u16x8*)&Bs[1][bkg + g2][bn][0] = pl[g2];
          *(u16x8*)&Bs[2][bkg + g2][bn][0] = pq[g2];
        }
      }
      __syncthreads();
      if (s + 1 < nsteps) {
        int kk = (s + 1) * 32;
        const u16* ap = xrow + (size_t)am * DD + kk + akg * 8;
        aR0 = *(const uint4*)ap;
        aR1 = *(const uint4*)(ap + (size_t)64 * DD);
        const float* wp = wrow + (size_t)bn * DD + kk + bko;
        bR0 = *(const float4*)(wp);
        bR1 = *(const float4*)(wp + 4);
        bR2 = *(const float4*)(wp + 8);
        bR3 = *(const float4*)(wp + 12);
      }
      bf16x8 af[2][2];
      #pragma unroll
      for (int mf = 0; mf < 2; mf++)
        #pragma unroll
        for (int h = 0; h < 2; h++)
          af[mf][h] = *(const bf16x8*)&As[2 * h + lh][wr + mf * 32 + lm][0];
      __builtin_amdgcn_s_setprio(1);   // favor MFMA waves vs co-resident filter waves
      #pragma unroll
      for (int p = 0; p < 3; p++) {
        bf16x8 bfr[2][2];
        #pragma unroll
        for (int nf = 0; nf < 2; nf++)
          #pragma unroll
          for (int h = 0; h < 2; h++)
            bfr[nf][h] = *(const bf16x8*)&Bs[p][2 * h + lh][wc + nf * 32 + lm][0];
        #pragma unroll
        for (int mf = 0; mf < 2; mf++)
          #pragma unroll
          for (int nf = 0; nf < 2; nf++) {
            acc[mf][nf] = __builtin_amdgcn_mfma_f32_32x32x16_bf16(af[mf][0], bfr[nf][0], acc[mf][nf], 0, 0, 0);
            acc[mf][nf] = __builtin_amdgcn_mfma_f32_32x32x16_bf16(af[mf][1], bfr[nf][1], acc[mf][nf], 0, 0, 0);
          }
      }
      __builtin_amdgcn_s_setprio(0);
    }

    float* Cp = Cpart + (size_t)kc * ((size_t)BB * DD);
    #pragma unroll
    for (int mf = 0; mf < 2; mf++)
      #pragma unroll
      for (int nf = 0; nf < 2; nf++) {
        int col   = nt * 128 + wc + nf * 32 + lm;
        int rbase = mt * 128 + wr + mf * 32 + 4 * lh;
        #pragma unroll
        for (int r = 0; r < 16; r++) {
          int row = rbase + (r & 3) + 8 * (r >> 2);
          Cp[(size_t)row * DD + col] = acc[mf][nf][r];
        }
      }
  } else {
    // ================= filter role (k_cand phase 1) =================
    int fb = (int)blockIdx.x - ngemm;
    int b = fb / MAXR, j = fb % MAXR;
    unsigned kk0 = keys[2*j], kk1 = keys[2*j+1];
    unsigned base = (unsigned)(b * DD);

    __shared__ int fcnt;
    __shared__ u16 fl[CAPG];
    if (t == 0) fcnt = 0;
    __syncthreads();

    #pragma unroll
    for (int p = 0; p < 16; p++) {
      int d = t + 256*p;
      unsigned bits = tf_xor(kk0, kk1, 0u, base + (unsigned)d);
      float f = bits_to_unit(bits);
      if (f >= U_THRESH) {
        int pos = atomicAdd(&fcnt, 1);
        if (pos < CAPG) fl[pos] = (u16)d;
      }
    }
    __syncthreads();
    int n = fcnt;
    if (t == 0) flt_cnt[fb] = n;
    int nstore = n < CAPG ? n : CAPG;
    if (t < nstore) flt_list[(size_t)fb * CAPG + t] = fl[t];
  }
}

// ---------------- K1c: reduce split-K, add bias, make sc_x ----------------
__global__ void k_reduce(const float* __restrict__ Cpart, const float* __restrict__ bias,
                         const float* __restrict__ x, float* __restrict__ grad,
                         float* __restrict__ sc, int KS) {
  int i = blockIdx.x * 256 + threadIdx.x;
  float acc = 0.0f;
  for (int kc = 0; kc < KS; kc++) acc += Cpart[(size_t)kc * BB * DD + i];
  float g = acc + bias[i & (DD-1)];
  grad[i] = g;
  float xv = x[i];
  sc[i] = (1.0f - 2.0f*xv) * g * 0.5f;
}

// ---------------- K2: score_x + per-row max of sc_x ----------------
__global__ __launch_bounds__(256) void k_score(const float* __restrict__ x, const float* __restrict__ grad,
                                               const float* __restrict__ bias, double* __restrict__ score,
                                               float* __restrict__ scmax) {
  int b = blockIdx.x, t = threadIdx.x;
  double s1 = 0.0, s2 = 0.0;
  float mx = -INFINITY;
  for (int k = 0; k < 16; k++) {
    int d = t + 256*k; size_t o = (size_t)b*DD + d;
    float xvf = x[o];
    float gv = grad[o];
    float scv = (1.0f - 2.0f*xvf) * gv * 0.5f;  // identical rounding to k_reduce
    mx = fmaxf(mx, scv);
    double xv = xvf;
    s1 += xv * (double)gv;
    s2 += xv * (double)bias[d];
  }
  __shared__ double lds[4];
  double S1 = blockReduce256(s1, lds);
  double S2 = blockReduce256(s2, lds);
  #pragma unroll
  for (int off = 32; off > 0; off >>= 1) mx = fmaxf(mx, __shfl_down(mx, off));
  __shared__ float lmx[4];
  __syncthreads();
  if ((t & 63) == 0) lmx[t >> 6] = mx;
  __syncthreads();
  if (t == 0) {
    score[b] = 0.5 * (S1 + S2);
    scmax[b] = fmaxf(fmaxf(lmx[0], lmx[1]), fmaxf(lmx[2], lmx[3]));
  }
}

// ---------------- K4: top-4 from prefiltered candidates + exact fallback ----------------
__global__ __launch_bounds__(256) void k_topk(const float* __restrict__ sc_x,
                                              const unsigned* __restrict__ keys,
                                              const float* __restrict__ scmax,
                                              const u16* __restrict__ flt_list,
                                              const int* __restrict__ flt_cnt,
                                              int* __restrict__ cand_i) {
  int fb = blockIdx.x;
  int b = fb / MAXR, j = fb % MAXR;
  unsigned kk0 = keys[2*j], kk1 = keys[2*j+1];
  int t = threadIdx.x;
  unsigned base = (unsigned)(b * DD);

  __shared__ float win_v_s;
  __shared__ int   win_i_s;
  __shared__ float ls_v[4];
  __shared__ int   ls_i[4];

  int n = flt_cnt[fb];
  bool need_fallback = (n > CAPG) || (n < NCAND);

  if (!need_fallback) {
    // exact gumbel + top-4 over <=CAPG candidates (1 per thread; n <= 192 < 256)
    float v; int di;
    if (t < n) {
      int d = (int)flt_list[(size_t)fb * CAPG + t];
      // recompute the SAME threefry draw bit-exactly
      float f = bits_to_unit(tf_xor(kk0, kk1, 0u, base + (unsigned)d));
      v = sc_x[(size_t)b*DD + d] + gumbel_from_u(f);
      di = d;
    } else { v = -INFINITY; di = 0x7FFFFFFF; }
    bool dead = (t >= n);
    float v4 = -INFINITY;
    for (int r = 0; r < NCAND; r++) {
      float bv = dead ? -INFINITY : v;
      int   bi = dead ? 0x7FFFFFFF : di;
      #pragma unroll
      for (int off = 32; off > 0; off >>= 1) {
        float ov = __shfl_down(bv, off);
        int   oi = __shfl_down(bi, off);
        if (ov > bv || (ov == bv && oi < bi)) { bv = ov; bi = oi; }
      }
      if ((t & 63) == 0) { ls_v[t >> 6] = bv; ls_i[t >> 6] = bi; }
      __syncthreads();
      if (t == 0) {
        float fv = ls_v[0]; int fi = ls_i[0];
        #pragma unroll
        for (int w = 1; w < 4; w++)
          if (ls_v[w] > fv || (ls_v[w] == fv && ls_i[w] < fi)) { fv = ls_v[w]; fi = ls_i[w]; }
        win_v_s = fv; win_i_s = fi;
        cand_i[(size_t)fb * NCAND + r] = fi;
      }
      __syncthreads();
      v4 = win_v_s;
      if (di == win_i_s) dead = true;
    }
    // guarantee: every skipped element has v < scmax + 3.8 < scmax + GUARD
    if (v4 >= scmax[b] + GUARD) return;
    need_fallback = true;
    __syncthreads();
  }

  // fallback: full exact computation (statistically ~never; preserves exactness)
  {
    float v[16];
    #pragma unroll
    for (int p = 0; p < 16; p++) {
      int d = t + 256*p;
      v[p] = sc_x[(size_t)b*DD + d] + gumbel_of(kk0, kk1, base + (unsigned)d);
    }
    unsigned alive = 0xFFFFu;
    float lv = -INFINITY; int li = 0x7FFFFFFF;
    #pragma unroll
    for (int p = 0; p < 16; p++)
      if (v[p] > lv) { lv = v[p]; li = t + 256*p; }
    for (int r = 0; r < NCAND; r++) {
      float bv = lv; int bi = li;
      #pragma unroll
      for (int off = 32; off > 0; off >>= 1) {
        float ov = __shfl_down(bv, off);
        int   oi = __shfl_down(bi, off);
        if (ov > bv || (ov == bv && oi < bi)) { bv = ov; bi = oi; }
      }
      if ((t & 63) == 0) { ls_v[t >> 6] = bv; ls_i[t >> 6] = bi; }
      __syncthreads();
      if (t == 0) {
        float fv = ls_v[0]; int fi = ls_i[0];
        #pragma unroll
        for (int w = 1; w < 4; w++)
          if (ls_v[w] > fv || (ls_v[w] == fv && ls_i[w] < fi)) { fv = ls_v[w]; fi = ls_i[w]; }
        win_i_s = fi;
        cand_i[(size_t)fb * NCAND + r] = fi;
      }
      __syncthreads();
      if (r < NCAND - 1) {
        int wi = win_i_s;
        if (t == (wi & 255)) {
          alive &= ~(1u << (wi >> 8));
          lv = -INFINITY; li = 0x7FFFFFFF;
          #pragma unroll
          for (int p = 0; p < 16; p++)
            if (((alive >> p) & 1u) && v[p] > lv) { lv = v[p]; li = t + 256*p; }
        }
      }
    }
  }
}

// ---------------- K5: per-row blocked-chain resolution w/ exact fallback ----------------
__global__ __launch_bounds__(256) void k_select(const int* __restrict__ cand_i,
                                                const float* __restrict__ sc_x,
                                                const unsigned* __restrict__ keys,
                                                int* __restrict__ idx_all) {
  int b = blockIdx.x, t = threadIdx.x;
  __shared__ unsigned mask[128];
  __shared__ int cl[MAXR * NCAND];
  __shared__ int pick_s;
  __shared__ float ls_v[4];
  __shared__ int   ls_i[4];
  if (t < 128) mask[t] = 0u;
  if (t < MAXR * NCAND) cl[t] = cand_i[(size_t)b * MAXR * NCAND + t];  // coalesced preload
  __syncthreads();
  for (int j = 0; j < MAXR; j++) {
    if (t == 0) {
      int pick = -1;
      #pragma unroll
      for (int r = 0; r < NCAND; r++) {
        int idx = cl[j * NCAND + r];
        if (pick < 0 && !((mask[idx >> 5] >> (idx & 31)) & 1u)) pick = idx;
      }
      pick_s = pick;
    }
    __syncthreads();
    if (pick_s < 0) {
      unsigned kk0 = keys[2*j], kk1 = keys[2*j+1];
      float lv = -INFINITY; int li = 0x7FFFFFFF;
      for (int p = 0; p < 16; p++) {
        int d = t + 256*p;
        if ((mask[d >> 5] >> (d & 31)) & 1u) continue;
        float vv = sc_x[(size_t)b*DD + d] + gumbel_of(kk0, kk1, (unsigned)(b*DD + d));
        if (vv > lv || (vv == lv && d < li)) { lv = vv; li = d; }
      }
      float bv = lv; int bi = li;
      #pragma unroll
      for (int off = 32; off > 0; off >>= 1) {
        float ov = __shfl_down(bv, off);
        int   oi = __shfl_down(bi, off);
        if (ov > bv || (ov == bv && oi < bi)) { bv = ov; bi = oi; }
      }
      if ((t & 63) == 0) { ls_v[t >> 6] = bv; ls_i[t >> 6] = bi; }
      __syncthreads();
      if (t == 0) {
        float fv = ls_v[0]; int fi = ls_i[0];
        #pragma unroll
        for (int w = 1; w < 4; w++)
          if (ls_v[w] > fv || (ls_v[w] == fv && ls_i[w] < fi)) { fv = ls_v[w]; fi = ls_i[w]; }
        pick_s = fi;
      }
      __syncthreads();
    }
    if (t == 0) {
      int pk = pick_s;
      idx_all[b*MAXR + j] = pk;
      mask[pk >> 5] |= (1u << (pk & 31));
    }
    __syncthreads();
  }
}

// ---------------- K6: y, grad_y (incremental), sc_y, score_y ----------------
__global__ __launch_bounds__(256) void k_y(const float* __restrict__ x, const float* __restrict__ W,
    const float* __restrict__ bias, const float* __restrict__ grad_x,
    const int* __restrict__ idx_all, const int* __restrict__ radius,
    float* __restrict__ yv, float* __restrict__ sc_y, double* __restrict__ score_y) {
  int b = blockIdx.x, t = threadIdx.x;
  __shared__ int   fidx[MAXR];
  __shared__ float fsgn[MAXR];
  int nf = radius[b];
  if (t < nf) {
    int id = idx_all[b*MAXR + t];
    fidx[t] = id;
    fsgn[t] = 1.0f - 2.0f * x[(size_t)b*DD + id];
  }
  __syncthreads();
  double s1 = 0.0, s2 = 0.0;
  for (int k = 0; k < 16; k++) {
    int d = t + 256*k;
    size_t o = (size_t)b*DD + d;
    float g = grad_x[o];
    float xval = x[o];
    float yval = xval;
    for (int jj = 0; jj < nf; jj++) {
      g = fmaf(fsgn[jj], W[(size_t)fidx[jj]*DD + d], g);
      if (fidx[jj] == d) yval = 1.0f - xval;
    }
    yv[o] = yval;
    sc_y[o] = (1.0f - 2.0f*yval) * g * 0.5f;
    s1 += (double)yval * (double)g;
    s2 += (double)yval * (double)bias[d];
  }
  __shared__ double lds[4];
  double S1 = blockReduce256(s1, lds);
  double S2 = blockReduce256(s2, lds);
  if (t == 0) score_y[b] = 0.5 * (S1 + S2);
}

// ---------------- K7: masked log-softmax sums, accept, output ----------------
__global__ __launch_bounds__(256) void k_accept(const float* __restrict__ x, const float* __restrict__ yv,
    const float* __restrict__ sc_x, const float* __restrict__ sc_y,
    const int* __restrict__ idx_all, const int* __restrict__ radius,
    const double* __restrict__ score_x, const double* __restrict__ score_y,
    const float* __restrict__ u_acc, float* __restrict__ out) {
  int b = blockIdx.x, t = threadIdx.x;
  __shared__ float scx_s[MAXR], scy_s[MAXR];
  if (t < MAXR) {
    int id = idx_all[b*MAXR + t];
    scx_s[t] = sc_x[(size_t)b*DD + id];
    scy_s[t] = sc_y[(size_t)b*DD + id];
  }
  double sx = 0.0, sy = 0.0;
  for (int k = 0; k < 16; k++) {
    int d = t + 256*k; size_t o = (size_t)b*DD + d;
    sx += exp((double)sc_x[o]);
    sy += exp((double)sc_y[o]);
  }
  __shared__ double lds[4];
  double S = blockReduce256(sx, lds);
  double T = blockReduce256(sy, lds);
  __shared__ float accf;
  if (t == 0) {
    int nf = radius[b];
    double lf = 0.0, pre = 0.0;
    for (int jj = 0; jj < MAXR; jj++) {
      double scv = (double)scx_s[jj];
      if (jj < nf) lf += scv - dlog(S - pre);
      pre += exp(scv);
    }
    double lb = 0.0, suf = 0.0;
    for (int jj = MAXR-1; jj >= 0; jj--) {
      double scv = (double)scy_s[jj];
      if (jj < nf) lb += scv - dlog(T - suf);
      suf += exp(scv);
    }
    double log_acc = (lb + score_y[b]) - (lf + score_x[b]);
    accf = (exp(log_acc) >= (double)u_acc[b]) ? 1.0f : 0.0f;
  }
  __syncthreads();
  float a = accf;
  for (int k = 0; k < 16; k++) {
    int d = t + 256*k; size_t o = (size_t)b*DD + d;
    out[o] = a * yv[o] + (1.0f - a) * x[o];
  }
}

extern "C" void kernel_launch(void* const* d_in, const int* in_sizes, int n_in,
                              void* d_out, int out_size, void* d_ws, size_t ws_size,
                              hipStream_t stream) {
  const float* x    = (const float*)d_in[0];
  const float* W    = (const float*)d_in[1];
  const float* bias = (const float*)d_in[2];
  float* out = (float*)d_out;
  char* ws = (char*)d_ws;
  const size_t MB = 1ull << 20;
  const size_t KB = 1024;

  float*    grad_x   = (float*)   (ws + 0*MB);
  float*    sc_x     = (float*)   (ws + 4*MB);
  float*    sc_y     = (float*)   (ws + 8*MB);
  float*    yv       = (float*)   (ws + 12*MB);
  u16*      xb       = (u16*)     (ws + 16*MB);                 // 2 MB
  u16*      flt_list = (u16*)     (ws + 18*MB);                 // 7936*192*2 = 2.91 MB
  int*      flt_cnt  = (int*)     (ws + 21*MB + 0*KB);          // 32 KB
  int*      cand_i   = (int*)     (ws + 21*MB + 32*KB);         // 124 KB
  int*      idx_all  = (int*)     (ws + 21*MB + 160*KB);        // 32 KB
  int*      radius   = (int*)     (ws + 21*MB + 192*KB);
  float*    u_acc    = (float*)   (ws + 21*MB + 196*KB);
  unsigned* keys     = (unsigned*)(ws + 21*MB + 200*KB);
  double*   score_x  = (double*)  (ws + 21*MB + 204*KB);
  double*   score_y  = (double*)  (ws + 21*MB + 208*KB);
  float*    scmax    = (float*)   (ws + 21*MB + 212*KB);
  float*    Cpart    = (float*)   (ws + 22*MB);

  size_t base = 22*MB;
  int KS = 1;
  if      (ws_size >= base + 16*MB) KS = 4;   // 256 gemm blocks = 1/CU (overlap sweet spot)
  else if (ws_size >= base +  8*MB) KS = 2;

  int NG = (DD/128) * (BB/128) * KS;

  k_rng   <<<1, 256, 0, stream>>>(keys, radius, u_acc);
  k_xbf16 <<<BB*DD/1024, 256, 0, stream>>>(x, xb);
  k_mega  <<<NG + BB*MAXR, 256, 0, stream>>>(xb, W, Cpart, DD/KS, NG, keys, flt_list, flt_cnt);
  k_reduce<<<BB*DD/256, 256, 0, stream>>>(Cpart, bias, x, grad_x, sc_x, KS);
  k_score <<<BB, 256, 0, stream>>>(x, grad_x, bias, score_x, scmax);
  k_topk  <<<BB*MAXR, 256, 0, stream>>>(sc_x, keys, scmax, flt_list, flt_cnt, cand_i);
  k_select<<<BB, 256, 0, stream>>>(cand_i, sc_x, keys, idx_all);
  k_y     <<<BB, 256, 0, stream>>>(x, W, bias, grad_x, idx_all, radius, yv, sc_y, score_y);
  k_accept<<<BB, 256, 0, stream>>>(x, yv, sc_x, sc_y, idx_all, radius, score_x, score_y, u_acc, out);
}

// Round 4
// 254.684 us; speedup vs baseline: 1.4711x; 1.2156x over previous
//
#include <hip/hip_runtime.h>
#include <math.h>

#define BB 256
#define DD 4096
#define MAXR 31
#define NCAND 4
#define CAPG 192
// filter: u < U_THRESH  =>  g(u) < 3.8 (incl. fp32 rounding slop). GUARD=4.0 check.
#define U_THRESH 0.9778f
#define GUARD 4.0f

typedef unsigned short u16;
typedef u16 u16x4 __attribute__((ext_vector_type(4)));
typedef u16 u16x8 __attribute__((ext_vector_type(8)));
typedef __bf16 bf16x8 __attribute__((ext_vector_type(8)));
typedef float f32x16 __attribute__((ext_vector_type(16)));

// ---------------- threefry2x32 (JAX schedule) ----------------
__device__ __forceinline__ void tf2x32(unsigned k0, unsigned k1, unsigned c0, unsigned c1,
                                       unsigned &o0, unsigned &o1) {
  unsigned ks2 = k0 ^ k1 ^ 0x1BD11BDAu;
  unsigned x0 = c0 + k0;
  unsigned x1 = c1 + k1;
#define TF_ROT(v, r) (((v) << (r)) | ((v) >> (32 - (r))))
#define TF_R(r) { x0 += x1; x1 = TF_ROT(x1, r); x1 ^= x0; }
  TF_R(13) TF_R(15) TF_R(26) TF_R(6)   x0 += k1;  x1 += ks2 + 1u;
  TF_R(17) TF_R(29) TF_R(16) TF_R(24)  x0 += ks2; x1 += k0 + 2u;
  TF_R(13) TF_R(15) TF_R(26) TF_R(6)   x0 += k0;  x1 += k1 + 3u;
  TF_R(17) TF_R(29) TF_R(16) TF_R(24)  x0 += k1;  x1 += ks2 + 4u;
  TF_R(13) TF_R(15) TF_R(26) TF_R(6)   x0 += ks2; x1 += k0 + 5u;
#undef TF_R
#undef TF_ROT
  o0 = x0; o1 = x1;
}

__device__ __forceinline__ unsigned tf_xor(unsigned k0, unsigned k1, unsigned c0, unsigned c1) {
  unsigned a, b; tf2x32(k0, k1, c0, c1, a, b); return a ^ b;
}

__device__ __forceinline__ float bits_to_unit(unsigned bits) {
  return __uint_as_float(0x3f800000u | (bits >> 9)) - 1.0f;
}

// sampling key for step j (bit-identical to old k_rng chain)
__device__ __forceinline__ void keys_of(int j, unsigned &kk0, unsigned &kk1) {
  unsigned ks0, ks1;
  tf2x32(0u, 42u, 0u, 1u, ks0, ks1);
  tf2x32(ks0, ks1, 0u, (unsigned)j, kk0, kk1);
}

__device__ __forceinline__ int radius_of(int b) {
  unsigned krad0, krad1, k10, k11, k20, k21;
  tf2x32(0u, 42u, 0u, 0u, krad0, krad1);
  tf2x32(krad0, krad1, 0u, 0u, k10, k11);
  tf2x32(krad0, krad1, 0u, 1u, k20, k21);
  unsigned hi = tf_xor(k10, k11, 0u, (unsigned)b);
  unsigned lo = tf_xor(k20, k21, 0u, (unsigned)b);
  return 1 + (int)(((hi % 31u) * 4u + (lo % 31u)) % 31u);
}

__device__ __forceinline__ float uacc_of(int b) {
  unsigned ka0, ka1;
  tf2x32(0u, 42u, 0u, 2u, ka0, ka1);
  return bits_to_unit(tf_xor(ka0, ka1, 0u, (unsigned)b));
}

// ---------------- fast accurate double log (~1e-13 rel) ----------------
__device__ __forceinline__ double dlog(double x) {
  unsigned long long ub = (unsigned long long)__double_as_longlong(x);
  int e = (int)((ub >> 52) & 0x7FFull) - 1022;
  double m = __longlong_as_double((long long)((ub & 0x000FFFFFFFFFFFFFull) | 0x3FE0000000000000ull));
  if (m < 0.70710678118654752440) { m *= 2.0; e -= 1; }
  double r = (m - 1.0) / (m + 1.0);
  double z = r * r;
  double s = fma(z, fma(z, fma(z, fma(z, fma(z, fma(z, 1.0/15.0, 1.0/13.0),
                1.0/11.0), 1.0/9.0), 1.0/7.0), 1.0/5.0), 1.0/3.0);
  double t2 = 2.0 * r;
  return fma((double)e, 0.69314718055994530942, fma(t2 * z, s, t2));
}

// gumbel from uniform u (u>0), fp32-rounded at each log (matches XLA)
__device__ __forceinline__ float gumbel_from_u(float f) {
  float uu = (f == 0.0f) ? 1.17549435e-38f : f;
  float t1 = (float)dlog((double)uu);
  return -(float)dlog((double)(-t1));
}

__device__ __forceinline__ float gumbel_of(unsigned kk0, unsigned kk1, unsigned n) {
  return gumbel_from_u(bits_to_unit(tf_xor(kk0, kk1, 0u, n)));
}

// 1024-thread double reduce (16 waves)
__device__ __forceinline__ double blockReduce1024(double v, double* lds) {
  int t = threadIdx.x;
  #pragma unroll
  for (int off = 32; off > 0; off >>= 1) v += __shfl_down(v, off);
  __syncthreads();
  if ((t & 63) == 0) lds[t >> 6] = v;
  __syncthreads();
  double s = 0.0;
  #pragma unroll
  for (int i = 0; i < 16; i++) s += lds[i];
  return s;
}

// ---------------- W 3-way bf16 split ----------------
__device__ __forceinline__ void split3(float w, u16 &h, u16 &l, u16 &q) {
  __bf16 hb = (__bf16)w;
  float r = w - (float)hb;        // exact
  __bf16 lb = (__bf16)r;
  float r2 = r - (float)lb;       // exact
  __bf16 qb = (__bf16)r2;
  h = __builtin_bit_cast(u16, hb);
  l = __builtin_bit_cast(u16, lb);
  q = __builtin_bit_cast(u16, qb);
}

// ---------------- K_MEGA: heterogeneous blocks ----------------
// blocks [0, ngemm):       128x64-tile bf16 3-split MFMA GEMM (matrix pipe)
// blocks [ngemm, +B*MAXR): threefry u-filter (VALU pipe)
// LDS/block = 20.8KB -> ~6-7 blocks/CU co-resident (the round-2 33KB gave only 2.3).
__global__ __launch_bounds__(256, 2) void k_mega(
    const float* __restrict__ x, const float* __restrict__ W,
    float* __restrict__ Cpart, int klen, int ngemm,
    u16* __restrict__ flt_list, int* __restrict__ flt_cnt) {
  int t = threadIdx.x;

  if ((int)blockIdx.x < ngemm) {
    // ================= GEMM role (M=128, N=64, K-step=32) =================
    int g = blockIdx.x;
    int nt = g & 63, mt = (g >> 6) & 1, kc = g >> 7;
    int k0 = kc * klen;

    __shared__ alignas(16) u16 As[4][128][8];     // 8 KB  (x tile bf16)
    __shared__ alignas(16) u16 Bs[3][4][64][8];   // 12 KB (Wh/Wl/Wl2)

    const float* xrow = x + (size_t)(mt * 128) * DD + k0;
    const float* wrow = W + (size_t)(nt * 64) * DD + k0;   // W symmetric: rows give B^T

    int am = t >> 2, akg = t & 3;   // A: rows am, am+64; k-group akg (8 floats)
    int bn = t >> 2, bkg = t & 3;   // B: row bn; k-group bkg

    float4 aR0, aR1, aR2, aR3;      // A row am (8 f32), row am+64 (8 f32)
    float4 bR0, bR1;                // B row bn (8 f32)
    int nsteps = klen / 32;

    { // prefetch step 0
      const float* ap = xrow + (size_t)am * DD + akg * 8;
      aR0 = *(const float4*)ap;       aR1 = *(const float4*)(ap + 4);
      const float* ap2 = ap + (size_t)64 * DD;
      aR2 = *(const float4*)ap2;      aR3 = *(const float4*)(ap2 + 4);
      const float* wp = wrow + (size_t)bn * DD + bkg * 8;
      bR0 = *(const float4*)wp;       bR1 = *(const float4*)(wp + 4);
    }

    int wid = t >> 6, lane = t & 63;
    int wr = (wid >> 1) * 64, wc = (wid & 1) * 32;  // wave's 64x32 quadrant
    int lm = lane & 31, lh = lane >> 5;

    f32x16 acc[2];
    #pragma unroll
    for (int i = 0; i < 2; i++)
      #pragma unroll
      for (int r = 0; r < 16; r++) acc[i][r] = 0.0f;

    for (int s = 0; s < nsteps; s++) {
      __syncthreads();
      { // A convert (exact: x in {0,1}) + write
        float af32[8];
        *(float4*)&af32[0] = aR0; *(float4*)&af32[4] = aR1;
        u16x8 av;
        #pragma unroll
        for (int i = 0; i < 8; i++) av[i] = __builtin_bit_cast(u16, (__bf16)af32[i]);
        *(u16x8*)&As[akg][am][0] = av;
        *(float4*)&af32[0] = aR2; *(float4*)&af32[4] = aR3;
        #pragma unroll
        for (int i = 0; i < 8; i++) av[i] = __builtin_bit_cast(u16, (__bf16)af32[i]);
        *(u16x8*)&As[akg][am + 64][0] = av;
      }
      { // B split3 + write 3 planes
        float wv[8];
        *(float4*)&wv[0] = bR0; *(float4*)&wv[4] = bR1;
        u16x8 ph, pl, pq;
        #pragma unroll
        for (int i = 0; i < 8; i++) {
          u16 hh, ll, qq;
          split3(wv[i], hh, ll, qq);
          ph[i] = hh; pl[i] = ll; pq[i] = qq;
        }
        *(u16x8*)&Bs[0][bkg][bn][0] = ph;
        *(u16x8*)&Bs[1][bkg][bn][0] = pl;
        *(u16x8*)&Bs[2][bkg][bn][0] = pq;
      }
      __syncthreads();
      if (s + 1 < nsteps) { // prefetch next step (hidden under MFMA)
        int kk = (s + 1) * 32;
        const float* ap = xrow + (size_t)am * DD + kk + akg * 8;
        aR0 = *(const float4*)ap;       aR1 = *(const float4*)(ap + 4);
        const float* ap2 = ap + (size_t)64 * DD;
        aR2 = *(const float4*)ap2;      aR3 = *(const float4*)(ap2 + 4);
        const float* wp = wrow + (size_t)bn * DD + kk + bkg * 8;
        bR0 = *(const float4*)wp;       bR1 = *(const float4*)(wp + 4);
      }
      // compute: 12 x v_mfma_f32_32x32x16_bf16 (same per-element accumulation order as before)
      bf16x8 af[2][2];
      #pragma unroll
      for (int mf = 0; mf < 2; mf++)
        #pragma unroll
        for (int h = 0; h < 2; h++)
          af[mf][h] = *(const bf16x8*)&As[2 * h + lh][wr + mf * 32 + lm][0];
      __builtin_amdgcn_s_setprio(1);
      #pragma unroll
      for (int p = 0; p < 3; p++) {
        bf16x8 b0 = *(const bf16x8*)&Bs[p][lh][wc + lm][0];       // h=0: kg=lh
        bf16x8 b1 = *(const bf16x8*)&Bs[p][2 + lh][wc + lm][0];   // h=1: kg=2+lh
        #pragma unroll
        for (int mf = 0; mf < 2; mf++) {
          acc[mf] = __builtin_amdgcn_mfma_f32_32x32x16_bf16(af[mf][0], b0, acc[mf], 0, 0, 0);
          acc[mf] = __builtin_amdgcn_mfma_f32_32x32x16_bf16(af[mf][1], b1, acc[mf], 0, 0, 0);
        }
      }
      __builtin_amdgcn_s_setprio(0);
    }

    float* Cp = Cpart + (size_t)kc * ((size_t)BB * DD);
    #pragma unroll
    for (int mf = 0; mf < 2; mf++) {
      int col   = nt * 64 + wc + lm;
      int rbase = mt * 128 + wr + mf * 32 + 4 * lh;
      #pragma unroll
      for (int r = 0; r < 16; r++) {
        int row = rbase + (r & 3) + 8 * (r >> 2);
        Cp[(size_t)row * DD + col] = acc[mf][r];
      }
    }
  } else {
    // ================= filter role =================
    int fb = (int)blockIdx.x - ngemm;
    int b = fb / MAXR, j = fb % MAXR;
    unsigned kk0, kk1;
    keys_of(j, kk0, kk1);
    unsigned base = (unsigned)(b * DD);

    __shared__ int fcnt;
    __shared__ u16 fl[CAPG];
    if (t == 0) fcnt = 0;
    __syncthreads();

    #pragma unroll
    for (int p = 0; p < 16; p++) {
      int d = t + 256*p;
      unsigned bits = tf_xor(kk0, kk1, 0u, base + (unsigned)d);
      float f = bits_to_unit(bits);
      if (f >= U_THRESH) {
        int pos = atomicAdd(&fcnt, 1);
        if (pos < CAPG) fl[pos] = (u16)d;
      }
    }
    __syncthreads();
    int n = fcnt;
    if (t == 0) flt_cnt[fb] = n;
    int nstore = n < CAPG ? n : CAPG;
    if (t < nstore) flt_list[(size_t)fb * CAPG + t] = fl[t];
  }
}

// ---------------- K_REDSCORE: split-K reduce + bias + sc_x + score_x + scmax ----------------
__global__ __launch_bounds__(1024) void k_redscore(
    const float* __restrict__ Cpart, const float* __restrict__ bias,
    const float* __restrict__ x, float* __restrict__ grad, float* __restrict__ sc,
    double* __restrict__ score, float* __restrict__ scmax, int KS) {
  int b = blockIdx.x, t = threadIdx.x;
  int d0 = t * 4;
  size_t o = (size_t)b * DD + d0;
  float a0 = 0.f, a1 = 0.f, a2 = 0.f, a3 = 0.f;
  for (int kc = 0; kc < KS; kc++) {
    float4 c = *(const float4*)&Cpart[(size_t)kc * BB * DD + o];
    a0 += c.x; a1 += c.y; a2 += c.z; a3 += c.w;
  }
  float4 bv = *(const float4*)&bias[d0];
  float4 xv = *(const float4*)&x[o];
  float gg[4] = { a0 + bv.x, a1 + bv.y, a2 + bv.z, a3 + bv.w };
  float xx[4] = { xv.x, xv.y, xv.z, xv.w };
  float bb[4] = { bv.x, bv.y, bv.z, bv.w };
  *(float4*)&grad[o] = *(float4*)&gg[0];
  float scv[4];
  double s1 = 0.0, s2 = 0.0;
  float mx = -INFINITY;
  #pragma unroll
  for (int k = 0; k < 4; k++) {
    scv[k] = (1.0f - 2.0f * xx[k]) * gg[k] * 0.5f;
    mx = fmaxf(mx, scv[k]);
    s1 += (double)xx[k] * (double)gg[k];
    s2 += (double)xx[k] * (double)bb[k];
  }
  *(float4*)&sc[o] = *(float4*)&scv[0];
  __shared__ double lds[16];
  double S1 = blockReduce1024(s1, lds);
  double S2 = blockReduce1024(s2, lds);
  #pragma unroll
  for (int off = 32; off > 0; off >>= 1) mx = fmaxf(mx, __shfl_down(mx, off));
  __shared__ float lmx[16];
  __syncthreads();
  if ((t & 63) == 0) lmx[t >> 6] = mx;
  __syncthreads();
  if (t == 0) {
    float m = lmx[0];
    #pragma unroll
    for (int i = 1; i < 16; i++) m = fmaxf(m, lmx[i]);
    score[b] = 0.5 * (S1 + S2);
    scmax[b] = m;
  }
}

// ---------------- K_TOPK: top-4 from prefiltered candidates + exact fallback ----------------
__global__ __launch_bounds__(256) void k_topk(const float* __restrict__ sc_x,
                                              const float* __restrict__ scmax,
                                              const u16* __restrict__ flt_list,
                                              const int* __restrict__ flt_cnt,
                                              int* __restrict__ cand_i) {
  int fb = blockIdx.x;
  int b = fb / MAXR, j = fb % MAXR;
  unsigned kk0, kk1;
  keys_of(j, kk0, kk1);
  int t = threadIdx.x;
  unsigned base = (unsigned)(b * DD);

  __shared__ float win_v_s;
  __shared__ int   win_i_s;
  __shared__ float ls_v[4];
  __shared__ int   ls_i[4];

  int n = flt_cnt[fb];
  bool need_fallback = (n > CAPG) || (n < NCAND);

  if (!need_fallback) {
    float v; int di;
    if (t < n) {
      int d = (int)flt_list[(size_t)fb * CAPG + t];
      float f = bits_to_unit(tf_xor(kk0, kk1, 0u, base + (unsigned)d));
      v = sc_x[(size_t)b*DD + d] + gumbel_from_u(f);
      di = d;
    } else { v = -INFINITY; di = 0x7FFFFFFF; }
    bool dead = (t >= n);
    float v4 = -INFINITY;
    for (int r = 0; r < NCAND; r++) {
      float bv = dead ? -INFINITY : v;
      int   bi = dead ? 0x7FFFFFFF : di;
      #pragma unroll
      for (int off = 32; off > 0; off >>= 1) {
        float ov = __shfl_down(bv, off);
        int   oi = __shfl_down(bi, off);
        if (ov > bv || (ov == bv && oi < bi)) { bv = ov; bi = oi; }
      }
      if ((t & 63) == 0) { ls_v[t >> 6] = bv; ls_i[t >> 6] = bi; }
      __syncthreads();
      if (t == 0) {
        float fv = ls_v[0]; int fi = ls_i[0];
        #pragma unroll
        for (int w = 1; w < 4; w++)
          if (ls_v[w] > fv || (ls_v[w] == fv && ls_i[w] < fi)) { fv = ls_v[w]; fi = ls_i[w]; }
        win_v_s = fv; win_i_s = fi;
        cand_i[(size_t)fb * NCAND + r] = fi;
      }
      __syncthreads();
      v4 = win_v_s;
      if (di == win_i_s) dead = true;
    }
    if (v4 >= scmax[b] + GUARD) return;
    need_fallback = true;
    __syncthreads();
  }

  // fallback: full exact computation (statistically ~never)
  {
    float v[16];
    #pragma unroll
    for (int p = 0; p < 16; p++) {
      int d = t + 256*p;
      v[p] = sc_x[(size_t)b*DD + d] + gumbel_of(kk0, kk1, base + (unsigned)d);
    }
    unsigned alive = 0xFFFFu;
    float lv = -INFINITY; int li = 0x7FFFFFFF;
    #pragma unroll
    for (int p = 0; p < 16; p++)
      if (v[p] > lv) { lv = v[p]; li = t + 256*p; }
    for (int r = 0; r < NCAND; r++) {
      float bv = lv; int bi = li;
      #pragma unroll
      for (int off = 32; off > 0; off >>= 1) {
        float ov = __shfl_down(bv, off);
        int   oi = __shfl_down(bi, off);
        if (ov > bv || (ov == bv && oi < bi)) { bv = ov; bi = oi; }
      }
      if ((t & 63) == 0) { ls_v[t >> 6] = bv; ls_i[t >> 6] = bi; }
      __syncthreads();
      if (t == 0) {
        float fv = ls_v[0]; int fi = ls_i[0];
        #pragma unroll
        for (int w = 1; w < 4; w++)
          if (ls_v[w] > fv || (ls_v[w] == fv && ls_i[w] < fi)) { fv = ls_v[w]; fi = ls_i[w]; }
        win_i_s = fi;
        cand_i[(size_t)fb * NCAND + r] = fi;
      }
      __syncthreads();
      if (r < NCAND - 1) {
        int wi = win_i_s;
        if (t == (wi & 255)) {
          alive &= ~(1u << (wi >> 8));
          lv = -INFINITY; li = 0x7FFFFFFF;
          #pragma unroll
          for (int p = 0; p < 16; p++)
            if (((alive >> p) & 1u) && v[p] > lv) { lv = v[p]; li = t + 256*p; }
        }
      }
    }
  }
}

// ---------------- K_SELY: chain resolution + y/sc_y/score_y ----------------
__global__ __launch_bounds__(1024) void k_sely(
    const int* __restrict__ cand_i, const float* __restrict__ sc_x,
    const float* __restrict__ x, const float* __restrict__ W,
    const float* __restrict__ bias, const float* __restrict__ grad_x,
    int* __restrict__ idx_all, float* __restrict__ yv, float* __restrict__ sc_y,
    double* __restrict__ score_y) {
  int b = blockIdx.x, t = threadIdx.x;
  __shared__ unsigned mask[128];
  __shared__ int cl[MAXR * NCAND];
  __shared__ int fidx[MAXR];
  __shared__ float fsgn[MAXR];
  __shared__ int jfail_s;
  __shared__ int nf_s;
  __shared__ float ls_v[16];
  __shared__ int   ls_i[16];
  if (t < 128) mask[t] = 0u;
  if (t < MAXR * NCAND) cl[t] = cand_i[(size_t)b * MAXR * NCAND + t];
  if (t == 0) nf_s = radius_of(b);
  __syncthreads();

  // --- select phase: serial t==0 chain, cooperative fallback only on blocked step ---
  int jdone = 0;
  while (true) {
    if (t == 0) {
      int j = jdone;
      while (j < MAXR) {
        int pick = -1;
        #pragma unroll
        for (int r = 0; r < NCAND; r++) {
          int idx = cl[j * NCAND + r];
          if (pick < 0 && !((mask[idx >> 5] >> (idx & 31)) & 1u)) pick = idx;
        }
        if (pick < 0) break;
        fidx[j] = pick;
        idx_all[b * MAXR + j] = pick;
        mask[pick >> 5] |= (1u << (pick & 31));
        j++;
      }
      jfail_s = j;
    }
    __syncthreads();
    int jf = jfail_s;
    if (jf >= MAXR) break;
    // cooperative exact fallback for step jf
    {
      unsigned kk0, kk1;
      keys_of(jf, kk0, kk1);
      float lv = -INFINITY; int li = 0x7FFFFFFF;
      #pragma unroll
      for (int q = 0; q < 4; q++) {
        int d = t * 4 + q;
        if ((mask[d >> 5] >> (d & 31)) & 1u) continue;
        float vv = sc_x[(size_t)b*DD + d] + gumbel_of(kk0, kk1, (unsigned)(b*DD + d));
        if (vv > lv || (vv == lv && d < li)) { lv = vv; li = d; }
      }
      #pragma unroll
      for (int off = 32; off > 0; off >>= 1) {
        float ov = __shfl_down(lv, off);
        int   oi = __shfl_down(li, off);
        if (ov > lv || (ov == lv && oi < li)) { lv = ov; li = oi; }
      }
      if ((t & 63) == 0) { ls_v[t >> 6] = lv; ls_i[t >> 6] = li; }
      __syncthreads();
      if (t == 0) {
        float fv = ls_v[0]; int fi = ls_i[0];
        #pragma unroll
        for (int w = 1; w < 16; w++)
          if (ls_v[w] > fv || (ls_v[w] == fv && ls_i[w] < fi)) { fv = ls_v[w]; fi = ls_i[w]; }
        fidx[jf] = fi;
        idx_all[b * MAXR + jf] = fi;
        mask[fi >> 5] |= (1u << (fi & 31));
      }
      __syncthreads();
    }
    jdone = jf + 1;
  }

  // --- y phase ---
  int nf = nf_s;
  if (t < nf) fsgn[t] = 1.0f - 2.0f * x[(size_t)b*DD + fidx[t]];
  __syncthreads();

  int d0 = t * 4;
  size_t o = (size_t)b * DD + d0;
  float4 gv4 = *(const float4*)&grad_x[o];
  float4 xv4 = *(const float4*)&x[o];
  float4 bv4 = *(const float4*)&bias[d0];
  float g[4]  = { gv4.x, gv4.y, gv4.z, gv4.w };
  float xx[4] = { xv4.x, xv4.y, xv4.z, xv4.w };
  float yy[4] = { xv4.x, xv4.y, xv4.z, xv4.w };
  for (int jj = 0; jj < nf; jj++) {
    int fd = fidx[jj];
    float s = fsgn[jj];
    float4 wv = *(const float4*)&W[(size_t)fd * DD + d0];
    g[0] = fmaf(s, wv.x, g[0]);
    g[1] = fmaf(s, wv.y, g[1]);
    g[2] = fmaf(s, wv.z, g[2]);
    g[3] = fmaf(s, wv.w, g[3]);
    int r = fd - d0;
    if (r >= 0 && r < 4) yy[r] = 1.0f - xx[r];
  }
  float scy[4];
  double s1 = 0.0, s2 = 0.0;
  float bb[4] = { bv4.x, bv4.y, bv4.z, bv4.w };
  #pragma unroll
  for (int k = 0; k < 4; k++) {
    scy[k] = (1.0f - 2.0f * yy[k]) * g[k] * 0.5f;
    s1 += (double)yy[k] * (double)g[k];
    s2 += (double)yy[k] * (double)bb[k];
  }
  *(float4*)&yv[o]   = *(float4*)&yy[0];
  *(float4*)&sc_y[o] = *(float4*)&scy[0];
  __shared__ double lds[16];
  double S1 = blockReduce1024(s1, lds);
  double S2 = blockReduce1024(s2, lds);
  if (t == 0) score_y[b] = 0.5 * (S1 + S2);
}

// ---------------- K_ACCEPT: masked log-softmax sums, accept, output ----------------
__global__ __launch_bounds__(1024) void k_accept(
    const float* __restrict__ x, const float* __restrict__ yv,
    const float* __restrict__ sc_x, const float* __restrict__ sc_y,
    const int* __restrict__ idx_all,
    const double* __restrict__ score_x, const double* __restrict__ score_y,
    float* __restrict__ out) {
  int b = blockIdx.x, t = threadIdx.x;
  __shared__ float scx_s[MAXR], scy_s[MAXR];
  __shared__ int nf_s;
  if (t < MAXR) {
    int id = idx_all[b*MAXR + t];
    scx_s[t] = sc_x[(size_t)b*DD + id];
    scy_s[t] = sc_y[(size_t)b*DD + id];
  }
  if (t == 0) nf_s = radius_of(b);

  int d0 = t * 4;
  size_t o = (size_t)b * DD + d0;
  float4 sxv = *(const float4*)&sc_x[o];
  float4 syv = *(const float4*)&sc_y[o];
  double sx = exp((double)sxv.x) + exp((double)sxv.y) + exp((double)sxv.z) + exp((double)sxv.w);
  double sy = exp((double)syv.x) + exp((double)syv.y) + exp((double)syv.z) + exp((double)syv.w);
  __shared__ double lds[16];
  double S = blockReduce1024(sx, lds);
  double T = blockReduce1024(sy, lds);
  __shared__ float accf;
  __syncthreads();
  if (t < 32) {
    int nf = nf_s;
    int lane = t;  // all in wave 0
    // forward: pre_t = sum_{i<t} exp(scx_i) via scan
    double ex = (t < MAXR) ? exp((double)scx_s[t]) : 0.0;
    double scn = ex;
    #pragma unroll
    for (int off = 1; off < 32; off <<= 1) {
      double ov = __shfl_up(scn, off);
      if (lane >= off) scn += ov;
    }
    double pre = scn - ex;
    double gf = (t < nf) ? ((double)scx_s[t] - dlog(S - pre)) : 0.0;
    // backward: suf_t = sum_{i>t} exp(scy_i) via reverse scan
    double ey = (t < MAXR) ? exp((double)scy_s[t]) : 0.0;
    double scn2 = ey;
    #pragma unroll
    for (int off = 1; off < 32; off <<= 1) {
      double ov = __shfl_down(scn2, off);
      if (lane + off < 32) scn2 += ov;
    }
    double suf = scn2 - ey;
    double gb = (t < nf) ? ((double)scy_s[t] - dlog(T - suf)) : 0.0;
    // wave-sum lf, lb over lanes 0..31
    #pragma unroll
    for (int off = 16; off > 0; off >>= 1) {
      gf += __shfl_down(gf, off);
      gb += __shfl_down(gb, off);
    }
    if (t == 0) {
      double log_acc = (gb + score_y[b]) - (gf + score_x[b]);
      accf = (exp(log_acc) >= (double)uacc_of(b)) ? 1.0f : 0.0f;
    }
  }
  __syncthreads();
  float a = accf;
  float4 yv4 = *(const float4*)&yv[o];
  float4 xv4 = *(const float4*)&x[o];
  float4 ov4;
  ov4.x = a * yv4.x + (1.0f - a) * xv4.x;
  ov4.y = a * yv4.y + (1.0f - a) * xv4.y;
  ov4.z = a * yv4.z + (1.0f - a) * xv4.z;
  ov4.w = a * yv4.w + (1.0f - a) * xv4.w;
  *(float4*)&out[o] = ov4;
}

extern "C" void kernel_launch(void* const* d_in, const int* in_sizes, int n_in,
                              void* d_out, int out_size, void* d_ws, size_t ws_size,
                              hipStream_t stream) {
  const float* x    = (const float*)d_in[0];
  const float* W    = (const float*)d_in[1];
  const float* bias = (const float*)d_in[2];
  float* out = (float*)d_out;
  char* ws = (char*)d_ws;
  const size_t MB = 1ull << 20;
  const size_t KB = 1024;

  float*    grad_x   = (float*)   (ws + 0*MB);
  float*    sc_x     = (float*)   (ws + 4*MB);
  float*    sc_y     = (float*)   (ws + 8*MB);
  float*    yv       = (float*)   (ws + 12*MB);
  u16*      flt_list = (u16*)     (ws + 16*MB);                 // 7936*192*2 = 2.91 MB
  int*      flt_cnt  = (int*)     (ws + 19*MB + 0*KB);          // 32 KB
  int*      cand_i   = (int*)     (ws + 19*MB + 32*KB);         // 124 KB
  int*      idx_all  = (int*)     (ws + 19*MB + 160*KB);        // 32 KB
  double*   score_x  = (double*)  (ws + 19*MB + 192*KB);
  double*   score_y  = (double*)  (ws + 19*MB + 196*KB);
  float*    scmax    = (float*)   (ws + 19*MB + 200*KB);
  float*    Cpart    = (float*)   (ws + 20*MB);

  size_t base = 20*MB;
  int KS = 1;
  if      (ws_size >= base + 16*MB) KS = 4;
  else if (ws_size >= base +  8*MB) KS = 2;

  int NG = 64 * 2 * KS;   // N-tiles x M-tiles x split-K

  k_mega    <<<NG + BB*MAXR, 256, 0, stream>>>(x, W, Cpart, DD/KS, NG, flt_list, flt_cnt);
  k_redscore<<<BB, 1024, 0, stream>>>(Cpart, bias, x, grad_x, sc_x, score_x, scmax, KS);
  k_topk    <<<BB*MAXR, 256, 0, stream>>>(sc_x, scmax, flt_list, flt_cnt, cand_i);
  k_sely    <<<BB, 1024, 0, stream>>>(cand_i, sc_x, x, W, bias, grad_x, idx_all, yv, sc_y, score_y);
  k_accept  <<<BB, 1024, 0, stream>>>(x, yv, sc_x, sc_y, idx_all, score_x, score_y, out);
}